// Round 1
// 137.389 us; speedup vs baseline: 1.0269x; 1.0269x over previous
//
#include <hip/hip_runtime.h>
#include <math.h>

#define NN 50001
#define DD 128
#define NE 800000
#define GEMM_BLOCKS 782              // ceil(ceil(50001/16)/4)
#define EDGE_BLOCKS 3125             // ceil(800000/256)
#define WSTRIDE 132                  // LDS row stride in shorts (128+4 pad)

typedef __attribute__((ext_vector_type(8))) short short8;
typedef __attribute__((ext_vector_type(4))) float floatx4;

__device__ __forceinline__ unsigned short f2bf(float f) {
    unsigned u = __builtin_bit_cast(unsigned, f);
    u += 0x7fffu + ((u >> 16) & 1u);          // round-to-nearest-even
    return (unsigned short)(u >> 16);
}
__device__ __forceinline__ float bflo(unsigned u) {   // low 16 bits as bf16 -> f32
    return __builtin_bit_cast(float, u << 16);
}
__device__ __forceinline__ float bfhi(unsigned u) {   // high 16 bits as bf16 -> f32
    return __builtin_bit_cast(float, u & 0xffff0000u);
}
__device__ __forceinline__ float score(float att) {   // leaky-relu(0.2) then exp(x-1)
    att = att >= 0.f ? att : 0.2f * att;
    return __expf(att - 1.f);
}

// K1: blocks < GEMM_BLOCKS: item = emb @ W_scale + b_scale (bf16), fused a_src/a_dst.
//     (unchanged from previous round — near its ~45 MB streaming floor)
//     blocks >= GEMM_BLOCKS: row_ptr[n] = first edge with src >= n (overlaps GEMM).
__global__ void __launch_bounds__(256) k_gemm(const float* __restrict__ emb,
        const float* __restrict__ W, const float* __restrict__ b_scale,
        const float* __restrict__ W_att, const int* __restrict__ edge,
        unsigned short* __restrict__ item, float* __restrict__ a_src,
        float* __restrict__ a_dst, int* __restrict__ row_ptr,
        const float* __restrict__ b_att) {
    if (blockIdx.x >= GEMM_BLOCKS) {                    // ---- rowptr part ----
        int e = (blockIdx.x - GEMM_BLOCKS) * 256 + threadIdx.x;
        if (e >= NE) return;
        int s = edge[2 * e];
        if (e == 0) {
            for (int n = 0; n <= s; n++) row_ptr[n] = 0;
        } else {
            int p = edge[2 * (e - 1)];
            for (int n = p + 1; n <= s; n++) row_ptr[n] = e;
        }
        if (e == NE - 1) {
            for (int n = s + 1; n <= NN; n++) row_ptr[n] = NE;
        }
        return;
    }
    // ---- GEMM part: one wave per 16 nodes ----
    __shared__ unsigned short WTl[DD * WSTRIDE];        // 33792 B, [feature][k]
    {
        const float4* Wv = (const float4*)W;            // 4096 float4s, coalesced
        #pragma unroll
        for (int it = 0; it < 16; it++) {
            int f = it * 256 + threadIdx.x;
            int k = f >> 5;                             // contraction index
            int j4 = (f & 31) * 4;                      // feature columns j4..j4+3
            float4 w = Wv[f];
            WTl[(j4 + 0) * WSTRIDE + k] = f2bf(w.x);
            WTl[(j4 + 1) * WSTRIDE + k] = f2bf(w.y);
            WTl[(j4 + 2) * WSTRIDE + k] = f2bf(w.z);
            WTl[(j4 + 3) * WSTRIDE + k] = f2bf(w.w);
        }
    }
    __syncthreads();

    int wave = blockIdx.x * 4 + (threadIdx.x >> 6);
    int lane = threadIdx.x & 63;
    int base = wave * 16;
    if (base >= NN) return;
    int m = lane & 15, q = lane >> 4;
    int node = base + m;
    bool valid = node < NN;

    int row = valid ? node : NN - 1;
    const float* bp = emb + (long)row * DD + q * 8;
    short8 b[4];                                        // B-frag: emb row (node index)
    #pragma unroll
    for (int ks = 0; ks < 4; ks++) {
        float4 f0 = *(const float4*)(bp + ks * 32);
        float4 f1 = *(const float4*)(bp + ks * 32 + 4);
        b[ks][0] = (short)f2bf(f0.x); b[ks][1] = (short)f2bf(f0.y);
        b[ks][2] = (short)f2bf(f0.z); b[ks][3] = (short)f2bf(f0.w);
        b[ks][4] = (short)f2bf(f1.x); b[ks][5] = (short)f2bf(f1.y);
        b[ks][6] = (short)f2bf(f1.z); b[ks][7] = (short)f2bf(f1.w);
    }

    float p_src = 0.f, p_dst = 0.f;

    #pragma unroll
    for (int ft = 0; ft < 8; ft++) {
        floatx4 acc = {0.f, 0.f, 0.f, 0.f};
        const unsigned short* wrow = WTl + (ft * 16 + m) * WSTRIDE;  // A-frag: feature row
        #pragma unroll
        for (int ks = 0; ks < 4; ks++) {
            short8 a = *(const short8*)(wrow + ks * 32 + q * 8);     // ds_read_b128
            acc = __builtin_amdgcn_mfma_f32_16x16x32_bf16(a, b[ks], acc, 0, 0, 0);
        }
        int fo = ft * 16 + q * 4;
        float4 bs = *(const float4*)(b_scale + fo);
        float4 ws = *(const float4*)(W_att + fo);
        float4 wd = *(const float4*)(W_att + DD + fo);
        float v0 = acc[0] + bs.x, v1 = acc[1] + bs.y;
        float v2 = acc[2] + bs.z, v3 = acc[3] + bs.w;
        if (valid) {
            uint2 pk;
            pk.x = (unsigned)f2bf(v0) | ((unsigned)f2bf(v1) << 16);
            pk.y = (unsigned)f2bf(v2) | ((unsigned)f2bf(v3) << 16);
            *(uint2*)(item + (long)node * DD + fo) = pk;
        }
        p_src += v0 * ws.x + v1 * ws.y + v2 * ws.z + v3 * ws.w;
        p_dst += v0 * wd.x + v1 * wd.y + v2 * wd.z + v3 * wd.w;
    }
    // reduce over q (lane bits 4,5); node is fixed within the reduction
    p_src += __shfl_xor(p_src, 16, 64); p_src += __shfl_xor(p_src, 32, 64);
    p_dst += __shfl_xor(p_dst, 16, 64); p_dst += __shfl_xor(p_dst, 32, 64);
    if (q == 0 && valid) { a_src[node] = p_src + b_att[0]; a_dst[node] = p_dst; }
}

// K2 v2: one 16-lane group per node (4 nodes/wave).
// Batch-16 edge header fetch: lane t loads dst[j+t] (contiguous) + a_dst and computes
// its OWN score (16 scores per __expf instead of 16 redundant lanes on one edge).
// Item rows then gathered 4-deep via __shfl broadcast of (d, s): 4 x 256 B in flight
// per group. Per-lane partial ssum -> only 4 shfl_xor at the end, no acc reduction.
#define ACC8(S, U) \
    acc[0] += (S) * bflo((U).x); acc[1] += (S) * bfhi((U).x); \
    acc[2] += (S) * bflo((U).y); acc[3] += (S) * bfhi((U).y); \
    acc[4] += (S) * bflo((U).z); acc[5] += (S) * bfhi((U).z); \
    acc[6] += (S) * bflo((U).w); acc[7] += (S) * bfhi((U).w);

__global__ void __launch_bounds__(256) k_agg(const int* __restrict__ edge,
        const int* __restrict__ row_ptr, const unsigned short* __restrict__ item,
        const float* __restrict__ a_src, const float* __restrict__ a_dst,
        float* __restrict__ out) {
    int n = blockIdx.x * 16 + (threadIdx.x >> 4);
    int t = threadIdx.x & 15;
    if (n >= NN) return;

    int start = row_ptr[n];
    int len = row_ptr[n + 1] - start;
    float* op = out + (long)n * DD + t * 8;

    if (len <= 0) {
        float4 h = make_float4(0.5f, 0.5f, 0.5f, 0.5f);   // sigmoid(0)
        *(float4*)op = h;
        *(float4*)(op + 4) = h;
        return;
    }

    float asrc = a_src[n];                 // b_att already folded in
    const int* dp = edge + 2 * start + 1;  // dst stream, stride-2 ints
    const unsigned short* ip = item + t * 8;

    float acc[8] = {0.f, 0.f, 0.f, 0.f, 0.f, 0.f, 0.f, 0.f};
    float ssum = 0.f;

    for (int j = 0; j < len; j += 16) {
        int jj = j + t;
        int idx = jj < len ? jj : len - 1;
        int d = dp[2 * idx];               // 16 lanes, contiguous 128 B window
        float x = a_dst[d];                // scattered 4 B, L2-resident (200 KB)
        float s = (jj < len) ? score(asrc + x) : 0.f;
        ssum += s;

        int cnt = len - j;
        if (cnt > 16) cnt = 16;
        int kk = 0;
        for (; kk + 4 <= cnt; kk += 4) {
            int d0 = __shfl(d, kk, 16),     d1 = __shfl(d, kk + 1, 16);
            int d2 = __shfl(d, kk + 2, 16), d3 = __shfl(d, kk + 3, 16);
            float s0 = __shfl(s, kk, 16),     s1 = __shfl(s, kk + 1, 16);
            float s2 = __shfl(s, kk + 2, 16), s3 = __shfl(s, kk + 3, 16);
            uint4 u0 = *(const uint4*)(ip + (long)d0 * DD);
            uint4 u1 = *(const uint4*)(ip + (long)d1 * DD);
            uint4 u2 = *(const uint4*)(ip + (long)d2 * DD);
            uint4 u3 = *(const uint4*)(ip + (long)d3 * DD);
            ACC8(s0, u0);
            ACC8(s1, u1);
            ACC8(s2, u2);
            ACC8(s3, u3);
        }
        for (; kk < cnt; kk++) {
            int d0 = __shfl(d, kk, 16);
            float s0 = __shfl(s, kk, 16);
            uint4 u0 = *(const uint4*)(ip + (long)d0 * DD);
            ACC8(s0, u0);
        }
    }

    // ssum reduce across the 16-lane group only (acc needs no reduction)
    ssum += __shfl_xor(ssum, 1, 16);
    ssum += __shfl_xor(ssum, 2, 16);
    ssum += __shfl_xor(ssum, 4, 16);
    ssum += __shfl_xor(ssum, 8, 16);
    float inv = 1.f / ssum;

    float4 o0, o1;
    o0.x = 1.f / (1.f + __expf(-acc[0] * inv));
    o0.y = 1.f / (1.f + __expf(-acc[1] * inv));
    o0.z = 1.f / (1.f + __expf(-acc[2] * inv));
    o0.w = 1.f / (1.f + __expf(-acc[3] * inv));
    o1.x = 1.f / (1.f + __expf(-acc[4] * inv));
    o1.y = 1.f / (1.f + __expf(-acc[5] * inv));
    o1.z = 1.f / (1.f + __expf(-acc[6] * inv));
    o1.w = 1.f / (1.f + __expf(-acc[7] * inv));
    *(float4*)op = o0;
    *(float4*)(op + 4) = o1;
}

extern "C" void kernel_launch(void* const* d_in, const int* in_sizes, int n_in,
                              void* d_out, int out_size, void* d_ws, size_t ws_size,
                              hipStream_t stream) {
    const int*   edge    = (const int*)d_in[0];
    const float* emb     = (const float*)d_in[1];
    const float* W_scale = (const float*)d_in[2];
    const float* b_scale = (const float*)d_in[3];
    const float* W_att   = (const float*)d_in[4];
    const float* b_att   = (const float*)d_in[5];
    float* out = (float*)d_out;

    char* ws = (char*)d_ws;
    int*            row_ptr = (int*)(ws);                                // 200832 B
    float*          a_src   = (float*)(ws + 200832);                     // 200192 B
    float*          a_dst   = (float*)(ws + 401024);                     // 200192 B
    unsigned short* item    = (unsigned short*)(ws + 601216);            // 12800256 B

    int node_blocks = (NN + 15) / 16;        // one 16-lane group per node

    k_gemm <<<GEMM_BLOCKS + EDGE_BLOCKS, 256, 0, stream>>>(emb, W_scale, b_scale, W_att,
                                                           edge, item, a_src, a_dst,
                                                           row_ptr, b_att);
    k_agg  <<<node_blocks,               256, 0, stream>>>(edge, row_ptr, item,
                                                           a_src, a_dst, out);
}